// Round 9
// baseline (308.221 us; speedup 1.0000x reference)
//
#include <hip/hip_runtime.h>

#define N_NODES 50000
#define N_EDGES 800000
#define C_IN 128
#define C_HID 256
#define C_OUT 128
#define BN_EPS 1e-5f

typedef __bf16 v8bf __attribute__((ext_vector_type(8)));
typedef float f32x4 __attribute__((ext_vector_type(4)));

// ---------- bf16 helpers (round-to-nearest-even) ----------
static __device__ __forceinline__ unsigned short f2bf(float f) {
    unsigned int u = __float_as_uint(f);
    u += 0x7fffu + ((u >> 16) & 1u);
    return (unsigned short)(u >> 16);
}
static __device__ __forceinline__ float bf2f(unsigned short h) {
    return __uint_as_float((unsigned int)h << 16);
}
static __device__ __forceinline__ unsigned int pack2(float a, float b) {
    return (unsigned int)f2bf(a) | ((unsigned int)f2bf(b) << 16);
}
static __device__ __forceinline__ float lo2f(unsigned int u) { return __uint_as_float(u << 16); }
static __device__ __forceinline__ float hi2f(unsigned int u) { return __uint_as_float(u & 0xffff0000u); }

#define DEG_BLOCKS ((N_EDGES + 255) / 256)

// ---------------- degree + weight transpose (fused launch) ----------------

__global__ __launch_bounds__(256) void k_deg_wtrans(const int* __restrict__ dst, int* __restrict__ deg,
                                                    const float* __restrict__ W1, const float* __restrict__ W2,
                                                    unsigned short* __restrict__ WT1, unsigned short* __restrict__ WT2) {
    int bx = blockIdx.x, t = threadIdx.x;
    if (bx < DEG_BLOCKS) {
        int e = bx * 256 + t;
        if (e < N_EDGES) atomicAdd(&deg[dst[e]], 1);
    } else {
        int i = (bx - DEG_BLOCKS) * 256 + t;  // [0, 65536)
        if (i < C_IN * C_HID) {               // WT1[n][k] = W1[k][n]
            int n = i >> 7, k = i & 127;
            WT1[n * C_IN + k] = f2bf(W1[k * C_HID + n]);
        } else {
            int j = i - C_IN * C_HID;         // WT2[n][k] = W2[k][n]
            int n = j >> 8, k = j & 255;
            WT2[n * C_HID + k] = f2bf(W2[k * C_OUT + n]);
        }
    }
}

// ---------------- CSR build ----------------

__global__ __launch_bounds__(512) void k_scan1(const int* __restrict__ deg, int* __restrict__ rs,
                                               int* __restrict__ partial, float* __restrict__ dis) {
    __shared__ int s[512];
    int t = threadIdx.x;
    int i = blockIdx.x * 512 + t;
    int v = (i < N_NODES) ? deg[i] : 0;
    if (i < N_NODES) dis[i] = rsqrtf((float)v + 1.0f);
    s[t] = v;
    __syncthreads();
    for (int off = 1; off < 512; off <<= 1) {
        int tv = (t >= off) ? s[t - off] : 0;
        __syncthreads();
        s[t] += tv;
        __syncthreads();
    }
    if (i < N_NODES) rs[i + 1] = s[t];
    if (t == 511) partial[blockIdx.x] = s[511];
}

// fused scan2+scan3
__global__ __launch_bounds__(256) void k_scan23(int* __restrict__ rs, const int* __restrict__ partial,
                                                int* __restrict__ cur, int nb) {
    __shared__ int pre[128];
    __shared__ int wsum[2];
    int t = threadIdx.x;
    int lane = t & 63;
    int pv = 0, v = 0;
    if (t < 128) {
        pv = (t < nb) ? partial[t] : 0;
        v = pv;
#pragma unroll
        for (int off = 1; off < 64; off <<= 1) {
            int u = __shfl_up(v, off);
            if (lane >= off) v += u;
        }
        if (lane == 63) wsum[t >> 6] = v;
    }
    __syncthreads();
    if (t < 128) {
        if (t >= 64) v += wsum[0];
        pre[t] = v - pv;
    }
    __syncthreads();
    int i = blockIdx.x * 256 + t;
    if (i < N_NODES) {
        int vv = rs[i + 1] + pre[i >> 9];
        rs[i + 1] = vv;
        cur[i + 1] = vv;
    }
    if (i == 0) { rs[0] = 0; cur[0] = 0; }
}

// ---------------- dst-sliced scatter + x-prescale (fused launch) ----------------

#define SCAT_GROUPS 256
#define NODES_PER_SLICE (N_NODES / 8)
#define EDGES_PER_CHUNK ((N_EDGES + SCAT_GROUPS - 1) / SCAT_GROUPS)
#define SCAT_BLOCKS (SCAT_GROUPS * 8)

__global__ __launch_bounds__(256) void k_scatter_xscale(const int* __restrict__ src, const int* __restrict__ dst,
                                                        int* __restrict__ cur, int* __restrict__ eidx,
                                                        const float* __restrict__ x, const float* __restrict__ dis,
                                                        unsigned short* __restrict__ xs) {
    int bx = blockIdx.x, t = threadIdx.x;
    if (bx < SCAT_BLOCKS) {
        int slice = bx & 7;
        int g = bx >> 3;
        int lo = slice * NODES_PER_SLICE;
        int hi = lo + NODES_PER_SLICE;
        int e0 = g * EDGES_PER_CHUNK;
        int e1 = e0 + EDGES_PER_CHUNK;
        if (e1 > N_EDGES) e1 = N_EDGES;
        for (int e = e0 + t; e < e1; e += 256) {
            int d = dst[e];
            if (d >= lo && d < hi) {
                int pos = atomicAdd(&cur[d], 1);
                eidx[pos] = src[e];
            }
        }
    } else {
        int i = (bx - SCAT_BLOCKS) * 256 + t;
        int node = i >> 4;
        if (node < N_NODES) {
            int g8 = (i & 15) * 8;
            float d = dis[node];
            float4 v0 = *(const float4*)&x[(size_t)node * C_IN + g8];
            float4 v1 = *(const float4*)&x[(size_t)node * C_IN + g8 + 4];
            uint4 o = make_uint4(pack2(v0.x * d, v0.y * d), pack2(v0.z * d, v0.w * d),
                                 pack2(v1.x * d, v1.y * d), pack2(v1.z * d, v1.w * d));
            *(uint4*)&xs[(size_t)node * C_IN + g8] = o;
        }
    }
}

// ---------------- 128-ch row aggregate: one wave per node, 2 edges/instr ----------------

template <bool FINAL>
__global__ __launch_bounds__(256) void k_aggr(const unsigned short* __restrict__ g,
                                              const float* __restrict__ dis, const float* __restrict__ bias,
                                              const int* __restrict__ rs, const int* __restrict__ eidx,
                                              unsigned short* __restrict__ outb, float* __restrict__ outf) {
    int wid = (blockIdx.x * 256 + threadIdx.x) >> 6;
    int lane = threadIdx.x & 63;
    if (wid >= N_NODES) return;
    int slot = lane >> 5;
    int cp = lane & 31;
    int s = rs[wid], e = rs[wid + 1];
    float a0 = 0.f, a1 = 0.f, a2 = 0.f, a3 = 0.f;
    float c0 = 0.f, c1 = 0.f, c2 = 0.f, c3 = 0.f;
    int p = s;
    for (; p + 7 < e; p += 8) {
        int i0 = eidx[p + slot];
        int i1 = eidx[p + 2 + slot];
        int i2 = eidx[p + 4 + slot];
        int i3 = eidx[p + 6 + slot];
        ushort4 v0 = *(const ushort4*)&g[(size_t)i0 * 128 + cp * 4];
        ushort4 v1 = *(const ushort4*)&g[(size_t)i1 * 128 + cp * 4];
        ushort4 v2 = *(const ushort4*)&g[(size_t)i2 * 128 + cp * 4];
        ushort4 v3 = *(const ushort4*)&g[(size_t)i3 * 128 + cp * 4];
        a0 += bf2f(v0.x) + bf2f(v1.x); a1 += bf2f(v0.y) + bf2f(v1.y);
        a2 += bf2f(v0.z) + bf2f(v1.z); a3 += bf2f(v0.w) + bf2f(v1.w);
        c0 += bf2f(v2.x) + bf2f(v3.x); c1 += bf2f(v2.y) + bf2f(v3.y);
        c2 += bf2f(v2.z) + bf2f(v3.z); c3 += bf2f(v2.w) + bf2f(v3.w);
    }
    for (; p + 1 < e; p += 2) {
        int i0 = eidx[p + slot];
        ushort4 v0 = *(const ushort4*)&g[(size_t)i0 * 128 + cp * 4];
        a0 += bf2f(v0.x); a1 += bf2f(v0.y); a2 += bf2f(v0.z); a3 += bf2f(v0.w);
    }
    if (p < e && slot == 0) {
        int i0 = eidx[p];
        ushort4 v0 = *(const ushort4*)&g[(size_t)i0 * 128 + cp * 4];
        a0 += bf2f(v0.x); a1 += bf2f(v0.y); a2 += bf2f(v0.z); a3 += bf2f(v0.w);
    }
    a0 += c0; a1 += c1; a2 += c2; a3 += c3;
    a0 += __shfl_xor(a0, 32); a1 += __shfl_xor(a1, 32);
    a2 += __shfl_xor(a2, 32); a3 += __shfl_xor(a3, 32);
    if (slot == 0) {
        ushort4 gi = *(const ushort4*)&g[(size_t)wid * 128 + cp * 4];
        float d = dis[wid];
        if (FINAL) {
            float4 bv = *(const float4*)&bias[cp * 4];
            float4 o = make_float4(fmaf(d, a0 + bf2f(gi.x), bv.x), fmaf(d, a1 + bf2f(gi.y), bv.y),
                                   fmaf(d, a2 + bf2f(gi.z), bv.z), fmaf(d, a3 + bf2f(gi.w), bv.w));
            *(float4*)&outf[(size_t)wid * 128 + cp * 4] = o;
        } else {
            ushort4 z;
            z.x = f2bf(d * (a0 + bf2f(gi.x)));
            z.y = f2bf(d * (a1 + bf2f(gi.y)));
            z.z = f2bf(d * (a2 + bf2f(gi.z)));
            z.w = f2bf(d * (a3 + bf2f(gi.w)));
            *(ushort4*)&outb[(size_t)wid * 128 + cp * 4] = z;
        }
    }
}

// ---------------- MFMA bf16 GEMM, coalesced LDS-staged epilogue ----------------
// TRANS=false (GEMM1): C = bf16( A@B + bias[col] ), fused BN stats from stored values.
// TRANS=true  (GEMM2): A with BN/ReLU (coeffs from bnsum/bnsq in-kernel), C = bf16((A'@B)*dis[row]).
// Epilogue: acc -> LDS tile (reuses A/B staging memory) -> full-line dwordx4 stores
// (prev: 64 scalar 2B stores/thread -> 2x HBM write amplification, 59us @ 1.9% MfmaUtil).

#define GBM 128
#define GBK 64
#define LDA 72
#define PC 136   // C-tile LDS pitch (ushorts): 128+8, 16B-aligned rows, bank-spread

template <bool TRANS>
__global__ __launch_bounds__(256) void k_gemm(const unsigned short* __restrict__ Ah,
                                              const unsigned short* __restrict__ BT,
                                              unsigned short* __restrict__ C,
                                              const float* __restrict__ dis, const float* __restrict__ bias,
                                              float* __restrict__ bnsum, float* __restrict__ bnsq,
                                              const float* __restrict__ gamma, const float* __restrict__ beta,
                                              int M, int N, int K) {
    __shared__ char smem[GBM * LDA * 2 * 2];       // 36864B: Alds+Blds (K-loop) / Clds (epilogue)
    unsigned short* Alds = (unsigned short*)smem;
    unsigned short* Blds = Alds + GBM * LDA;
    unsigned short* Clds = (unsigned short*)smem;  // 128 x PC = 34816B
    __shared__ float ep_s[GBM];
    __shared__ float tsc_s[256];
    __shared__ float tof_s[256];
    __shared__ float bnS[128];
    __shared__ float bnQ[128];

    int t = threadIdx.x;
    int row0 = blockIdx.x * GBM;
    int col0 = blockIdx.y * GBM;
    int wave = t >> 6, lane = t & 63;
    int wm = wave & 1, wn = wave >> 1;
    int lm = lane & 15, quad = lane >> 4;

    if (TRANS) {
        if (t < GBM) ep_s[t] = (row0 + t < M) ? dis[row0 + t] : 0.f;
        float inv_n = 1.0f / (float)N_NODES;
        float mu = bnsum[t] * inv_n;
        float var = bnsq[t] * inv_n - mu * mu;
        float a = gamma[t] * rsqrtf(var + BN_EPS);
        tsc_s[t] = a;
        tof_s[t] = beta[t] - mu * a;
    } else {
        if (t < GBM) { ep_s[t] = bias[col0 + t]; bnS[t] = 0.f; bnQ[t] = 0.f; }
    }
    __syncthreads();

    int sr = t >> 1;
    int kb = (t & 1) * 32;

    f32x4 acc[4][4] = {};

    for (int kt = 0; kt < K; kt += GBK) {
        uint4 sa[4], sb[4];
        int r = row0 + sr;
#pragma unroll
        for (int j = 0; j < 4; ++j) {
            int k = kt + kb + 8 * j;
            uint4 h = (r < M) ? *(const uint4*)&Ah[(size_t)r * K + k] : make_uint4(0u, 0u, 0u, 0u);
            if (TRANS) {
                float4 s0 = *(const float4*)&tsc_s[k];
                float4 s1 = *(const float4*)&tsc_s[k + 4];
                float4 o0 = *(const float4*)&tof_s[k];
                float4 o1 = *(const float4*)&tof_s[k + 4];
                float f0 = fmaxf(fmaf(lo2f(h.x), s0.x, o0.x), 0.f);
                float f1 = fmaxf(fmaf(hi2f(h.x), s0.y, o0.y), 0.f);
                float f2 = fmaxf(fmaf(lo2f(h.y), s0.z, o0.z), 0.f);
                float f3 = fmaxf(fmaf(hi2f(h.y), s0.w, o0.w), 0.f);
                float f4 = fmaxf(fmaf(lo2f(h.z), s1.x, o1.x), 0.f);
                float f5 = fmaxf(fmaf(hi2f(h.z), s1.y, o1.y), 0.f);
                float f6 = fmaxf(fmaf(lo2f(h.w), s1.z, o1.z), 0.f);
                float f7 = fmaxf(fmaf(hi2f(h.w), s1.w, o1.w), 0.f);
                sa[j] = make_uint4(pack2(f0, f1), pack2(f2, f3), pack2(f4, f5), pack2(f6, f7));
            } else {
                sa[j] = h;
            }
            sb[j] = *(const uint4*)&BT[(size_t)(col0 + sr) * K + k];
        }
        __syncthreads();
#pragma unroll
        for (int j = 0; j < 4; ++j) {
            *(uint4*)&Alds[sr * LDA + kb + 8 * j] = sa[j];
            *(uint4*)&Blds[sr * LDA + kb + 8 * j] = sb[j];
        }
        __syncthreads();
#pragma unroll
        for (int kc = 0; kc < 2; ++kc) {
            v8bf af[4], bfv[4];
#pragma unroll
            for (int im = 0; im < 4; ++im)
                af[im] = *(const v8bf*)&Alds[(wm * 64 + im * 16 + lm) * LDA + kc * 32 + quad * 8];
#pragma unroll
            for (int in = 0; in < 4; ++in)
                bfv[in] = *(const v8bf*)&Blds[(wn * 64 + in * 16 + lm) * LDA + kc * 32 + quad * 8];
#pragma unroll
            for (int im = 0; im < 4; ++im)
#pragma unroll
                for (int in = 0; in < 4; ++in)
                    acc[im][in] = __builtin_amdgcn_mfma_f32_16x16x32_bf16(af[im], bfv[in], acc[im][in], 0, 0, 0);
        }
    }

    __syncthreads();  // K-loop LDS reads complete before reusing smem as Clds
#pragma unroll
    for (int im = 0; im < 4; ++im) {
        int rb = wm * 64 + im * 16 + quad * 4;
#pragma unroll
        for (int in = 0; in < 4; ++in) {
            f32x4 c = acc[im][in];
            int colLoc = wn * 64 + in * 16 + lm;
#pragma unroll
            for (int q = 0; q < 4; ++q) {
                float val = TRANS ? c[q] * ep_s[rb + q] : c[q] + ep_s[colLoc];
                Clds[(rb + q) * PC + colLoc] = f2bf(val);
            }
        }
    }
    __syncthreads();

    // coalesced store: thread t -> rows (t>>4)+16*it, 16B at col (t&15)*8; every 16-lane
    // group writes a full 256B segment (full cache lines). BN stats piggyback on the read.
    int rsub = t >> 4;
    int c8 = (t & 15) * 8;
    float ss[8] = {}, qq[8] = {};
#pragma unroll
    for (int it = 0; it < 8; ++it) {
        int rl = rsub + it * 16;
        int row = row0 + rl;
        if (row < M) {
            uint4 v = *(const uint4*)&Clds[rl * PC + c8];
            *(uint4*)&C[(size_t)row * N + col0 + c8] = v;
            if (!TRANS) {
                float f0 = lo2f(v.x), f1 = hi2f(v.x), f2 = lo2f(v.y), f3 = hi2f(v.y);
                float f4 = lo2f(v.z), f5 = hi2f(v.z), f6 = lo2f(v.w), f7 = hi2f(v.w);
                ss[0] += f0; qq[0] = fmaf(f0, f0, qq[0]);
                ss[1] += f1; qq[1] = fmaf(f1, f1, qq[1]);
                ss[2] += f2; qq[2] = fmaf(f2, f2, qq[2]);
                ss[3] += f3; qq[3] = fmaf(f3, f3, qq[3]);
                ss[4] += f4; qq[4] = fmaf(f4, f4, qq[4]);
                ss[5] += f5; qq[5] = fmaf(f5, f5, qq[5]);
                ss[6] += f6; qq[6] = fmaf(f6, f6, qq[6]);
                ss[7] += f7; qq[7] = fmaf(f7, f7, qq[7]);
            }
        }
    }
    if (!TRANS) {
#pragma unroll
        for (int j = 0; j < 8; ++j) {
            atomicAdd(&bnS[c8 + j], ss[j]);
            atomicAdd(&bnQ[c8 + j], qq[j]);
        }
        __syncthreads();
        if (t < 128) {
            atomicAdd(&bnsum[col0 + t], bnS[t]);
            atomicAdd(&bnsq[col0 + t], bnQ[t]);
        }
    }
}

// ---------------- launch ----------------

extern "C" void kernel_launch(void* const* d_in, const int* in_sizes, int n_in,
                              void* d_out, int out_size, void* d_ws, size_t ws_size,
                              hipStream_t stream) {
    const float* x      = (const float*)d_in[0];
    const int*   ei     = (const int*)d_in[1];
    const float* W1     = (const float*)d_in[2];
    const float* b1     = (const float*)d_in[3];
    const float* gamma1 = (const float*)d_in[4];
    const float* beta1  = (const float*)d_in[5];
    const float* W2     = (const float*)d_in[6];
    const float* b2     = (const float*)d_in[7];
    const int* srcv = ei;
    const int* dstv = ei + N_EDGES;
    float* out = (float*)d_out;

    char* w = (char*)d_ws;
    size_t off = 0;
    auto alloc = [&](size_t bytes) {
        void* p = w + off;
        off = (off + bytes + 255) & ~(size_t)255;
        return p;
    };
    int*   deg     = (int*)alloc(N_NODES * 4);
    float* bnsum   = (float*)alloc(256 * 4);
    float* bnsq    = (float*)alloc(256 * 4);
    size_t zero_bytes = off;                           // deg + bnsum + bnsq
    float* dis     = (float*)alloc(N_NODES * 4);
    int*   rs      = (int*)alloc((N_NODES + 1) * 4);
    int*   cur     = (int*)alloc((N_NODES + 1) * 4);
    int*   partial = (int*)alloc(128 * 4);
    int*   eidx    = (int*)alloc((size_t)N_EDGES * 4);
    unsigned short* WT1 = (unsigned short*)alloc((size_t)C_IN * C_HID * 2);
    unsigned short* WT2 = (unsigned short*)alloc((size_t)C_HID * C_OUT * 2);
    unsigned short* xs  = (unsigned short*)alloc((size_t)N_NODES * C_IN * 2);
    unsigned short* P   = (unsigned short*)alloc((size_t)N_NODES * C_IN * 2);
    unsigned short* z1  = (unsigned short*)alloc((size_t)N_NODES * C_HID * 2);
    unsigned short* g2  = (unsigned short*)alloc((size_t)N_NODES * C_OUT * 2);
    (void)ws_size; (void)in_sizes; (void)n_in; (void)out_size;

    hipMemsetAsync(deg, 0, zero_bytes, stream);

    int nb = (N_NODES + 511) / 512;  // 98
    k_deg_wtrans<<<DEG_BLOCKS + 256, 256, 0, stream>>>(dstv, deg, W1, W2, WT1, WT2);
    k_scan1<<<nb, 512, 0, stream>>>(deg, rs, partial, dis);
    k_scan23<<<(N_NODES + 255) / 256, 256, 0, stream>>>(rs, partial, cur, nb);
    k_scatter_xscale<<<SCAT_BLOCKS + (N_NODES * 16 + 255) / 256, 256, 0, stream>>>(
        srcv, dstv, cur, eidx, x, dis, xs);

    // layer 1 reassociated: P = Ahat @ X, then Z1 = P@W1 + b1 (+ fused BN stats)
    k_aggr<false><<<(N_NODES * 64 + 255) / 256, 256, 0, stream>>>(xs, dis, nullptr, rs, eidx, P, nullptr);
    dim3 gg1((N_NODES + GBM - 1) / GBM, C_HID / GBM);
    k_gemm<false><<<gg1, 256, 0, stream>>>(P, WT1, z1, nullptr, b1, bnsum, bnsq, nullptr, nullptr,
                                           N_NODES, C_HID, C_IN);

    // layer 2: g2 = dis * (relu(BN(z1)) @ W2), then out = Ahat-gather + b2
    dim3 gg2((N_NODES + GBM - 1) / GBM, C_OUT / GBM);
    k_gemm<true><<<gg2, 256, 0, stream>>>(z1, WT2, g2, dis, nullptr, bnsum, bnsq, gamma1, beta1,
                                          N_NODES, C_OUT, C_HID);
    k_aggr<true><<<(N_NODES * 64 + 255) / 256, 256, 0, stream>>>(g2, dis, b2, rs, eidx, nullptr, out);
}

// Round 10
// 287.232 us; speedup vs baseline: 1.0731x; 1.0731x over previous
//
#include <hip/hip_runtime.h>

#define N_NODES 50000
#define N_EDGES 800000
#define C_IN 128
#define C_HID 256
#define C_OUT 128
#define BN_EPS 1e-5f

typedef __bf16 v8bf __attribute__((ext_vector_type(8)));
typedef float f32x4 __attribute__((ext_vector_type(4)));

// ---------- bf16 helpers (round-to-nearest-even) ----------
static __device__ __forceinline__ unsigned short f2bf(float f) {
    unsigned int u = __float_as_uint(f);
    u += 0x7fffu + ((u >> 16) & 1u);
    return (unsigned short)(u >> 16);
}
static __device__ __forceinline__ float bf2f(unsigned short h) {
    return __uint_as_float((unsigned int)h << 16);
}
static __device__ __forceinline__ unsigned int pack2(float a, float b) {
    return (unsigned int)f2bf(a) | ((unsigned int)f2bf(b) << 16);
}
static __device__ __forceinline__ float lo2f(unsigned int u) { return __uint_as_float(u << 16); }
static __device__ __forceinline__ float hi2f(unsigned int u) { return __uint_as_float(u & 0xffff0000u); }

#define DEG_BLOCKS ((N_EDGES + 255) / 256)

// ---------------- degree + weight transpose (fused launch) ----------------

__global__ __launch_bounds__(256) void k_deg_wtrans(const int* __restrict__ dst, int* __restrict__ deg,
                                                    const float* __restrict__ W1, const float* __restrict__ W2,
                                                    unsigned short* __restrict__ WT1, unsigned short* __restrict__ WT2) {
    int bx = blockIdx.x, t = threadIdx.x;
    if (bx < DEG_BLOCKS) {
        int e = bx * 256 + t;
        if (e < N_EDGES) atomicAdd(&deg[dst[e]], 1);
    } else {
        int i = (bx - DEG_BLOCKS) * 256 + t;  // [0, 65536)
        if (i < C_IN * C_HID) {               // WT1[n][k] = W1[k][n]
            int n = i >> 7, k = i & 127;
            WT1[n * C_IN + k] = f2bf(W1[k * C_HID + n]);
        } else {
            int j = i - C_IN * C_HID;         // WT2[n][k] = W2[k][n]
            int n = j >> 8, k = j & 255;
            WT2[n * C_HID + k] = f2bf(W2[k * C_OUT + n]);
        }
    }
}

// ---------------- CSR build ----------------

__global__ __launch_bounds__(512) void k_scan1(const int* __restrict__ deg, int* __restrict__ rs,
                                               int* __restrict__ partial, float* __restrict__ dis) {
    __shared__ int s[512];
    int t = threadIdx.x;
    int i = blockIdx.x * 512 + t;
    int v = (i < N_NODES) ? deg[i] : 0;
    if (i < N_NODES) dis[i] = rsqrtf((float)v + 1.0f);
    s[t] = v;
    __syncthreads();
    for (int off = 1; off < 512; off <<= 1) {
        int tv = (t >= off) ? s[t - off] : 0;
        __syncthreads();
        s[t] += tv;
        __syncthreads();
    }
    if (i < N_NODES) rs[i + 1] = s[t];
    if (t == 511) partial[blockIdx.x] = s[511];
}

// fused scan2+scan3
__global__ __launch_bounds__(256) void k_scan23(int* __restrict__ rs, const int* __restrict__ partial,
                                                int* __restrict__ cur, int nb) {
    __shared__ int pre[128];
    __shared__ int wsum[2];
    int t = threadIdx.x;
    int lane = t & 63;
    int pv = 0, v = 0;
    if (t < 128) {
        pv = (t < nb) ? partial[t] : 0;
        v = pv;
#pragma unroll
        for (int off = 1; off < 64; off <<= 1) {
            int u = __shfl_up(v, off);
            if (lane >= off) v += u;
        }
        if (lane == 63) wsum[t >> 6] = v;
    }
    __syncthreads();
    if (t < 128) {
        if (t >= 64) v += wsum[0];
        pre[t] = v - pv;
    }
    __syncthreads();
    int i = blockIdx.x * 256 + t;
    if (i < N_NODES) {
        int vv = rs[i + 1] + pre[i >> 9];
        rs[i + 1] = vv;
        cur[i + 1] = vv;
    }
    if (i == 0) { rs[0] = 0; cur[0] = 0; }
}

// ---------------- dst-sliced scatter + x-prescale (fused launch) ----------------

#define SCAT_GROUPS 256
#define NODES_PER_SLICE (N_NODES / 8)
#define EDGES_PER_CHUNK ((N_EDGES + SCAT_GROUPS - 1) / SCAT_GROUPS)
#define SCAT_BLOCKS (SCAT_GROUPS * 8)

__global__ __launch_bounds__(256) void k_scatter_xscale(const int* __restrict__ src, const int* __restrict__ dst,
                                                        int* __restrict__ cur, int* __restrict__ eidx,
                                                        const float* __restrict__ x, const float* __restrict__ dis,
                                                        unsigned short* __restrict__ xs) {
    int bx = blockIdx.x, t = threadIdx.x;
    if (bx < SCAT_BLOCKS) {
        int slice = bx & 7;
        int g = bx >> 3;
        int lo = slice * NODES_PER_SLICE;
        int hi = lo + NODES_PER_SLICE;
        int e0 = g * EDGES_PER_CHUNK;
        int e1 = e0 + EDGES_PER_CHUNK;
        if (e1 > N_EDGES) e1 = N_EDGES;
        for (int e = e0 + t; e < e1; e += 256) {
            int d = dst[e];
            if (d >= lo && d < hi) {
                int pos = atomicAdd(&cur[d], 1);
                eidx[pos] = src[e];
            }
        }
    } else {
        int i = (bx - SCAT_BLOCKS) * 256 + t;
        int node = i >> 4;
        if (node < N_NODES) {
            int g8 = (i & 15) * 8;
            float d = dis[node];
            float4 v0 = *(const float4*)&x[(size_t)node * C_IN + g8];
            float4 v1 = *(const float4*)&x[(size_t)node * C_IN + g8 + 4];
            uint4 o = make_uint4(pack2(v0.x * d, v0.y * d), pack2(v0.z * d, v0.w * d),
                                 pack2(v1.x * d, v1.y * d), pack2(v1.z * d, v1.w * d));
            *(uint4*)&xs[(size_t)node * C_IN + g8] = o;
        }
    }
}

// ---------------- 128-ch row aggregate: one wave per node, 2 edges/instr ----------------

template <bool FINAL>
__global__ __launch_bounds__(256) void k_aggr(const unsigned short* __restrict__ g,
                                              const float* __restrict__ dis, const float* __restrict__ bias,
                                              const int* __restrict__ rs, const int* __restrict__ eidx,
                                              unsigned short* __restrict__ outb, float* __restrict__ outf) {
    int wid = (blockIdx.x * 256 + threadIdx.x) >> 6;
    int lane = threadIdx.x & 63;
    if (wid >= N_NODES) return;
    int slot = lane >> 5;
    int cp = lane & 31;
    int s = rs[wid], e = rs[wid + 1];
    float a0 = 0.f, a1 = 0.f, a2 = 0.f, a3 = 0.f;
    float c0 = 0.f, c1 = 0.f, c2 = 0.f, c3 = 0.f;
    int p = s;
    for (; p + 7 < e; p += 8) {
        int i0 = eidx[p + slot];
        int i1 = eidx[p + 2 + slot];
        int i2 = eidx[p + 4 + slot];
        int i3 = eidx[p + 6 + slot];
        ushort4 v0 = *(const ushort4*)&g[(size_t)i0 * 128 + cp * 4];
        ushort4 v1 = *(const ushort4*)&g[(size_t)i1 * 128 + cp * 4];
        ushort4 v2 = *(const ushort4*)&g[(size_t)i2 * 128 + cp * 4];
        ushort4 v3 = *(const ushort4*)&g[(size_t)i3 * 128 + cp * 4];
        a0 += bf2f(v0.x) + bf2f(v1.x); a1 += bf2f(v0.y) + bf2f(v1.y);
        a2 += bf2f(v0.z) + bf2f(v1.z); a3 += bf2f(v0.w) + bf2f(v1.w);
        c0 += bf2f(v2.x) + bf2f(v3.x); c1 += bf2f(v2.y) + bf2f(v3.y);
        c2 += bf2f(v2.z) + bf2f(v3.z); c3 += bf2f(v2.w) + bf2f(v3.w);
    }
    for (; p + 1 < e; p += 2) {
        int i0 = eidx[p + slot];
        ushort4 v0 = *(const ushort4*)&g[(size_t)i0 * 128 + cp * 4];
        a0 += bf2f(v0.x); a1 += bf2f(v0.y); a2 += bf2f(v0.z); a3 += bf2f(v0.w);
    }
    if (p < e && slot == 0) {
        int i0 = eidx[p];
        ushort4 v0 = *(const ushort4*)&g[(size_t)i0 * 128 + cp * 4];
        a0 += bf2f(v0.x); a1 += bf2f(v0.y); a2 += bf2f(v0.z); a3 += bf2f(v0.w);
    }
    a0 += c0; a1 += c1; a2 += c2; a3 += c3;
    a0 += __shfl_xor(a0, 32); a1 += __shfl_xor(a1, 32);
    a2 += __shfl_xor(a2, 32); a3 += __shfl_xor(a3, 32);
    if (slot == 0) {
        ushort4 gi = *(const ushort4*)&g[(size_t)wid * 128 + cp * 4];
        float d = dis[wid];
        if (FINAL) {
            float4 bv = *(const float4*)&bias[cp * 4];
            float4 o = make_float4(fmaf(d, a0 + bf2f(gi.x), bv.x), fmaf(d, a1 + bf2f(gi.y), bv.y),
                                   fmaf(d, a2 + bf2f(gi.z), bv.z), fmaf(d, a3 + bf2f(gi.w), bv.w));
            *(float4*)&outf[(size_t)wid * 128 + cp * 4] = o;
        } else {
            ushort4 z;
            z.x = f2bf(d * (a0 + bf2f(gi.x)));
            z.y = f2bf(d * (a1 + bf2f(gi.y)));
            z.z = f2bf(d * (a2 + bf2f(gi.z)));
            z.w = f2bf(d * (a3 + bf2f(gi.w)));
            *(ushort4*)&outb[(size_t)wid * 128 + cp * 4] = z;
        }
    }
}

// ---------------- MFMA bf16 GEMM, barrier-free M-streaming ----------------
// Block = 4 waves, 64-col panel. B-panel staged to LDS ONCE, fragments extracted to
// REGISTERS (GEMM1: 16 v8bf, GEMM2: 32 v8bf), then each wave independently streams
// 4 strips of 16 rows: A-frags loaded DIRECTLY from global (row-major == A-frag layout),
// MFMA vs register B, epilogue via per-wave LDS C-tile -> coalesced 128B stores.
// NO block barriers in the M-loop (fixes the 60us barrier-chain pathology: MfmaUtil 1.9%,
// all pipes idle). TRANS: BN+ReLU transform in-register per A-load (tsc/tof LDS broadcast).
// GEMM1 (!TRANS): C = bf16(A@B + bias[col]); BN stats in registers -> shfl reduce -> atomics.
// GEMM2 (TRANS):  C = bf16((relu(A*tsc+tof)@B) * dis[row]).

template <bool TRANS, int KC>   // K = KC*32
__global__ __launch_bounds__(256, 2) void k_gemmv(const unsigned short* __restrict__ Ah,
                                                  const unsigned short* __restrict__ BT,
                                                  unsigned short* __restrict__ C,
                                                  const float* __restrict__ dis, const float* __restrict__ bias,
                                                  float* __restrict__ bnsum, float* __restrict__ bnsq,
                                                  const float* __restrict__ gamma, const float* __restrict__ beta,
                                                  int M, int N) {
    constexpr int K = KC * 32;
    constexpr int BP = K + 8;                   // B LDS pitch (ushorts); rows 16B-aligned
    __shared__ unsigned short Blds[64 * BP];    // aliased as per-wave C-tiles after extraction
    __shared__ float tsc_s[K];
    __shared__ float tof_s[K];

    int t = threadIdx.x;
    int w = t >> 6, lane = t & 63;
    int lm = lane & 15, quad = lane >> 4;
    int col0 = blockIdx.y * 64;

    if (TRANS && t < K) {
        float inv_n = 1.0f / (float)N_NODES;
        float mu = bnsum[t] * inv_n;
        float var = bnsq[t] * inv_n - mu * mu;
        float a = gamma[t] * rsqrtf(var + BN_EPS);
        tsc_s[t] = a;
        tof_s[t] = beta[t] - mu * a;
    }
    // stage B panel (64 cols x K) to LDS
    constexpr int NLD = 64 * K / 8;
    for (int j = t; j < NLD; j += 256) {
        int n = j / (K / 8);
        int kq = j % (K / 8);
        *(uint4*)&Blds[n * BP + kq * 8] = *(const uint4*)&BT[(size_t)(col0 + n) * K + kq * 8];
    }
    __syncthreads();
    // extract B fragments to registers (row stride BP: 68/132 words %32 = 4 -> 2-way, free)
    v8bf bfr[4][KC];
#pragma unroll
    for (int in = 0; in < 4; ++in)
#pragma unroll
        for (int kc = 0; kc < KC; ++kc)
            bfr[in][kc] = *(const v8bf*)&Blds[(in * 16 + lm) * BP + kc * 32 + quad * 8];
    __syncthreads();    // B reads done; Blds becomes C-tile scratch

    unsigned short* Ct = Blds + w * (16 * 80);  // per-wave 16x64 tile, pitch 80 (quad-conflict-free)

    float bias_r[4];
    if (!TRANS) {
#pragma unroll
        for (int in = 0; in < 4; ++in) bias_r[in] = bias[col0 + in * 16 + lm];
    }
    float ss[4] = {0.f, 0.f, 0.f, 0.f}, qq[4] = {0.f, 0.f, 0.f, 0.f};

    int strip0 = (blockIdx.x * 4 + w) * 4;
#pragma unroll
    for (int s = 0; s < 4; ++s) {
        int strip = strip0 + s;
        if (strip * 16 >= M) break;             // M is a multiple of 16
        int arow = strip * 16 + lm;
        uint4 araw[KC];
#pragma unroll
        for (int kc = 0; kc < KC; ++kc)
            araw[kc] = *(const uint4*)&Ah[(size_t)arow * K + kc * 32 + quad * 8];
        float dqa[4];
        if (TRANS) *(float4*)dqa = *(const float4*)&dis[strip * 16 + quad * 4];
        f32x4 acc[4] = {};
#pragma unroll
        for (int kc = 0; kc < KC; ++kc) {
            v8bf af;
            if (TRANS) {
                int kb2 = kc * 32 + quad * 8;
                float4 s0 = *(const float4*)&tsc_s[kb2];
                float4 s1 = *(const float4*)&tsc_s[kb2 + 4];
                float4 o0 = *(const float4*)&tof_s[kb2];
                float4 o1 = *(const float4*)&tof_s[kb2 + 4];
                uint4 h = araw[kc];
                float f0 = fmaxf(fmaf(lo2f(h.x), s0.x, o0.x), 0.f);
                float f1 = fmaxf(fmaf(hi2f(h.x), s0.y, o0.y), 0.f);
                float f2 = fmaxf(fmaf(lo2f(h.y), s0.z, o0.z), 0.f);
                float f3 = fmaxf(fmaf(hi2f(h.y), s0.w, o0.w), 0.f);
                float f4 = fmaxf(fmaf(lo2f(h.z), s1.x, o1.x), 0.f);
                float f5 = fmaxf(fmaf(hi2f(h.z), s1.y, o1.y), 0.f);
                float f6 = fmaxf(fmaf(lo2f(h.w), s1.z, o1.z), 0.f);
                float f7 = fmaxf(fmaf(hi2f(h.w), s1.w, o1.w), 0.f);
                uint4 pk = make_uint4(pack2(f0, f1), pack2(f2, f3), pack2(f4, f5), pack2(f6, f7));
                af = *(v8bf*)&pk;
            } else {
                af = *(v8bf*)&araw[kc];
            }
#pragma unroll
            for (int in = 0; in < 4; ++in)
                acc[in] = __builtin_amdgcn_mfma_f32_16x16x32_bf16(af, bfr[in][kc], acc[in], 0, 0, 0);
        }
        // epilogue: pack into per-wave LDS tile (C/D layout: row=quad*4+q, col=in*16+lm)
#pragma unroll
        for (int in = 0; in < 4; ++in) {
#pragma unroll
            for (int q = 0; q < 4; ++q) {
                float val = TRANS ? acc[in][q] * dqa[q] : acc[in][q] + bias_r[in];
                unsigned short hb = f2bf(val);
                Ct[(quad * 4 + q) * 80 + in * 16 + lm] = hb;
                if (!TRANS) {
                    float v = bf2f(hb);
                    ss[in] += v;
                    qq[in] = fmaf(v, v, qq[in]);
                }
            }
        }
        // same-wave LDS round trip (in-order, no barrier) -> coalesced 16B stores
#pragma unroll
        for (int it = 0; it < 2; ++it) {
            int rl = (lane >> 3) + it * 8;
            uint4 v = *(const uint4*)&Ct[rl * 80 + (lane & 7) * 8];
            *(uint4*)&C[(size_t)(strip * 16 + rl) * N + col0 + (lane & 7) * 8] = v;
        }
    }
    if (!TRANS) {
#pragma unroll
        for (int in = 0; in < 4; ++in) {
            float s = ss[in], q2 = qq[in];
            s += __shfl_xor(s, 16); q2 += __shfl_xor(q2, 16);
            s += __shfl_xor(s, 32); q2 += __shfl_xor(q2, 32);
            if (quad == 0) {
                atomicAdd(&bnsum[col0 + in * 16 + lm], s);
                atomicAdd(&bnsq[col0 + in * 16 + lm], q2);
            }
        }
    }
}

// ---------------- launch ----------------

extern "C" void kernel_launch(void* const* d_in, const int* in_sizes, int n_in,
                              void* d_out, int out_size, void* d_ws, size_t ws_size,
                              hipStream_t stream) {
    const float* x      = (const float*)d_in[0];
    const int*   ei     = (const int*)d_in[1];
    const float* W1     = (const float*)d_in[2];
    const float* b1     = (const float*)d_in[3];
    const float* gamma1 = (const float*)d_in[4];
    const float* beta1  = (const float*)d_in[5];
    const float* W2     = (const float*)d_in[6];
    const float* b2     = (const float*)d_in[7];
    const int* srcv = ei;
    const int* dstv = ei + N_EDGES;
    float* out = (float*)d_out;

    char* w = (char*)d_ws;
    size_t off = 0;
    auto alloc = [&](size_t bytes) {
        void* p = w + off;
        off = (off + bytes + 255) & ~(size_t)255;
        return p;
    };
    int*   deg     = (int*)alloc(N_NODES * 4);
    float* bnsum   = (float*)alloc(256 * 4);
    float* bnsq    = (float*)alloc(256 * 4);
    size_t zero_bytes = off;                           // deg + bnsum + bnsq
    float* dis     = (float*)alloc(N_NODES * 4);
    int*   rs      = (int*)alloc((N_NODES + 1) * 4);
    int*   cur     = (int*)alloc((N_NODES + 1) * 4);
    int*   partial = (int*)alloc(128 * 4);
    int*   eidx    = (int*)alloc((size_t)N_EDGES * 4);
    unsigned short* WT1 = (unsigned short*)alloc((size_t)C_IN * C_HID * 2);
    unsigned short* WT2 = (unsigned short*)alloc((size_t)C_HID * C_OUT * 2);
    unsigned short* xs  = (unsigned short*)alloc((size_t)N_NODES * C_IN * 2);
    unsigned short* P   = (unsigned short*)alloc((size_t)N_NODES * C_IN * 2);
    unsigned short* z1  = (unsigned short*)alloc((size_t)N_NODES * C_HID * 2);
    unsigned short* g2  = (unsigned short*)alloc((size_t)N_NODES * C_OUT * 2);
    (void)ws_size; (void)in_sizes; (void)n_in; (void)out_size;

    hipMemsetAsync(deg, 0, zero_bytes, stream);

    int nb = (N_NODES + 511) / 512;  // 98
    k_deg_wtrans<<<DEG_BLOCKS + 256, 256, 0, stream>>>(dstv, deg, W1, W2, WT1, WT2);
    k_scan1<<<nb, 512, 0, stream>>>(deg, rs, partial, dis);
    k_scan23<<<(N_NODES + 255) / 256, 256, 0, stream>>>(rs, partial, cur, nb);
    k_scatter_xscale<<<SCAT_BLOCKS + (N_NODES * 16 + 255) / 256, 256, 0, stream>>>(
        srcv, dstv, cur, eidx, x, dis, xs);

    // layer 1 reassociated: P = Ahat @ X, then Z1 = P@W1 + b1 (+ fused BN stats)
    k_aggr<false><<<(N_NODES * 64 + 255) / 256, 256, 0, stream>>>(xs, dis, nullptr, rs, eidx, P, nullptr);
    dim3 gg1((N_NODES + 255) / 256, C_HID / 64);   // (196, 4)
    k_gemmv<false, 4><<<gg1, 256, 0, stream>>>(P, WT1, z1, nullptr, b1, bnsum, bnsq, nullptr, nullptr,
                                               N_NODES, C_HID);

    // layer 2: g2 = dis * (relu(BN(z1)) @ W2), then out = Ahat-gather + b2
    dim3 gg2((N_NODES + 255) / 256, C_OUT / 64);   // (196, 2)
    k_gemmv<true, 8><<<gg2, 256, 0, stream>>>(z1, WT2, g2, dis, nullptr, bnsum, bnsq, gamma1, beta1,
                                              N_NODES, C_OUT);
    k_aggr<true><<<(N_NODES * 64 + 255) / 256, 256, 0, stream>>>(g2, dis, b2, rs, eidx, nullptr, out);
}